// Round 2
// baseline (294.828 us; speedup 1.0000x reference)
//
#include <hip/hip_runtime.h>

// Problem constants (fixed by the reference)
#define B_N   8
#define S_N   2048
#define K_N   21
#define L_N   16
#define CM_N  256
#define SCHUNK 128
#define CHUNKS (S_N / SCHUNK)   // 16
#define WSTRIDE 260              // floats: 1040 B row stride -> 16B-aligned rows, bank-spread

typedef float vfloat4 __attribute__((ext_vector_type(4)));

__global__ __launch_bounds__(256, 4) void pssm_proj_kernel(
    const float* __restrict__ x,     // [B,S,K]
    const float* __restrict__ W,     // [L,CM,K]
    const float* __restrict__ bias,  // [L,CM]
    float* __restrict__ out)         // [B,L,S,CM]
{
    // Only W[l] lives in LDS now (transposed). x is read via wave-uniform
    // SCALAR loads in the hot loop -> no LDS pipe traffic, no lgkmcnt stall
    // on the row critical path.
    __shared__ float wt[K_N][WSTRIDE];

    const int tid   = threadIdx.x;
    const int bx    = blockIdx.x;
    const int chunk = bx % CHUNKS;
    const int l     = (bx / CHUNKS) % L_N;
    const int b     = bx / (CHUNKS * L_N);
    const int s0    = chunk * SCHUNK;

    // ---- stage W[l] -> LDS transposed (coalesced reads, once per block) ----
    const float* wbase = W + (size_t)l * CM_N * K_N;   // 5376 floats
    for (int idx = tid; idx < CM_N * K_N; idx += 256) {
        int c = idx / K_N;
        int k = idx - c * K_N;
        wt[k][c] = wbase[idx];
    }
    __syncthreads();

    // ---- per-lane W fragment from LDS: 21 conflict-free ds_read_b128 ----
    const int lane   = tid & 63;
    // readfirstlane makes the wave id PROVABLY uniform so x-row loads scalarize (s_load)
    const int wave_u = __builtin_amdgcn_readfirstlane(tid >> 6);
    const int c0     = lane * 4;

    vfloat4 wfv[K_N];   // wfv[k] = { W[l][c0+0][k], ..., W[l][c0+3][k] }
#pragma unroll
    for (int k = 0; k < K_N; ++k)
        wfv[k] = *(const vfloat4*)(&wt[k][c0]);

    vfloat4 bv = *(const vfloat4*)(bias + l * CM_N + c0);  // 16B-aligned coalesced

    const float* xw = x + ((size_t)b * S_N + s0) * K_N;    // wave-uniform base
    float* outp = out + (((size_t)b * L_N + l) * S_N + s0 + wave_u) * CM_N + c0;

    // each wave sweeps rows {wave, wave+4, ...}: 32 rows/wave.
    // unroll 2: row i+1's scalar loads issue under row i's FMA stream.
#pragma unroll 2
    for (int i = 0; i < SCHUNK / 4; ++i) {
        const int r = i * 4 + wave_u;               // wave-uniform row index
        const float* xr = xw + (size_t)r * K_N;     // uniform pointer -> SMEM loads

        float a0 = bv.x, a1 = bv.y, a2 = bv.z, a3 = bv.w;
#pragma unroll
        for (int k = 0; k < K_N; ++k) {
            const float xk = xr[k];   // scalar load, SGPR broadcast operand to v_fma
            a0 += xk * wfv[k].x;
            a1 += xk * wfv[k].y;
            a2 += xk * wfv[k].z;
            a3 += xk * wfv[k].w;
        }

        vfloat4 o = {a0, a1, a2, a3};
        *(vfloat4*)(outp + (size_t)i * 4 * CM_N) = o;   // 1KB/wave coalesced stream
    }
}

extern "C" void kernel_launch(void* const* d_in, const int* in_sizes, int n_in,
                              void* d_out, int out_size, void* d_ws, size_t ws_size,
                              hipStream_t stream) {
    const float* x    = (const float*)d_in[0];
    const float* W    = (const float*)d_in[1];
    const float* bias = (const float*)d_in[2];
    float* out        = (float*)d_out;

    dim3 grid(B_N * L_N * CHUNKS);   // 8*16*16 = 2048 blocks
    dim3 block(256);
    pssm_proj_kernel<<<grid, block, 0, stream>>>(x, W, bias, out);
}